// Round 2
// baseline (84.154 us; speedup 1.0000x reference)
//
#include <hip/hip_runtime.h>
#include <hip/hip_bf16.h>

// Problem constants (fixed by the reference file):
//   B=16 docs, PREV(K)=768, D(N)=256, lengths[i]=1024+128*i, T=31744, MAXLEN=2944
// Doc start offsets are multiples of 128 -> 64-row M-tiles never straddle docs.

#define T_TOTAL 31744
#define K_DIM   768
#define N_DIM   256
#define MAXLEN  2944
#define NKT     24          // K_DIM / 32

typedef __attribute__((ext_vector_type(8))) short    bf16x8;
typedef __attribute__((ext_vector_type(4))) short    short4v;
typedef __attribute__((ext_vector_type(4))) float    f32x4;
typedef __attribute__((ext_vector_type(4))) unsigned u32x4;

__device__ __forceinline__ unsigned short f2bf(float f) {
  unsigned u = __builtin_bit_cast(unsigned, f);
  u += 0x7fffu + ((u >> 16) & 1u);
  return (unsigned short)(u >> 16);
}

// v_cvt_pk_bf16_f32: one instr converts 2 f32 -> packed 2 bf16 (RNE).
__device__ __forceinline__ unsigned cvtpk(float lo, float hi) {
  unsigned r;
  asm("v_cvt_pk_bf16_f32 %0, %1, %2" : "=v"(r) : "v"(lo), "v"(hi));
  return r;
}

// ---------------------------------------------------------------------------
// Kernel 1: W [768][256] f32  ->  Wt [256][768] bf16 (workspace)
// ---------------------------------------------------------------------------
__global__ __launch_bounds__(256) void wt_transpose(const float* __restrict__ W,
                                                    unsigned short* __restrict__ Wt) {
  __shared__ unsigned short tile[64][68];
  const int b  = blockIdx.x;
  const int k0 = (b % 12) * 64;
  const int n0 = (b / 12) * 64;
  const int tid = threadIdx.x;
  const int rr = tid >> 4;
  const int cc = tid & 15;

#pragma unroll
  for (int i = 0; i < 4; ++i) {
    const int kr = i * 16 + rr;
    f32x4 v = *(const f32x4*)(W + (size_t)(k0 + kr) * N_DIM + n0 + cc * 4);
    tile[kr][cc * 4 + 0] = f2bf(v[0]);
    tile[kr][cc * 4 + 1] = f2bf(v[1]);
    tile[kr][cc * 4 + 2] = f2bf(v[2]);
    tile[kr][cc * 4 + 3] = f2bf(v[3]);
  }
  __syncthreads();
#pragma unroll
  for (int i = 0; i < 4; ++i) {
    const int nr = i * 16 + rr;
    short4v o;
#pragma unroll
    for (int j = 0; j < 4; ++j) o[j] = (short)tile[cc * 4 + j][nr];
    *(short4v*)(Wt + (size_t)(n0 + nr) * K_DIM + k0 + cc * 4) = o;
  }
}

// ---------------------------------------------------------------------------
// Kernel 2: zero only the padding rows of the [16*2944, 256] f32 output.
// ---------------------------------------------------------------------------
__global__ __launch_bounds__(256) void zero_pad(float* __restrict__ out) {
  const int gid = blockIdx.x * 256 + threadIdx.x;
  const int row = gid >> 6;
  const int doc = row / MAXLEN;
  const int within = row - doc * MAXLEN;
  const int len = 1024 + 128 * doc;
  if (within >= len) {
    f32x4 z = {0.f, 0.f, 0.f, 0.f};
    *(f32x4*)(out + (size_t)gid * 4) = z;
  }
}

// ---------------------------------------------------------------------------
// Kernel 3: GEMM + scatter — NO LDS, NO BARRIERS.
// 256 threads = 4 waves; BM=64, wave w owns cols w*64..w*64+63 (4x4 frags of
// mfma_f32_16x16x32_bf16). A-frags loaded straight from global fp32 in the
// MFMA lane pattern (2x16B/lane) and converted via v_cvt_pk_bf16_f32; B-frags
// loaded straight from the bf16 Wt (L2-resident). Depth-2 register prefetch:
// loads for kt+2 are in flight while kt computes; compiler inserts counted
// vmcnt on the register deps — no barrier drain anywhere.
// ---------------------------------------------------------------------------
__global__ __launch_bounds__(256, 2) void gemm_scatter(const float* __restrict__ A,
                                                       const unsigned short* __restrict__ Wt,
                                                       const float* __restrict__ bias,
                                                       float* __restrict__ out) {
  const int tid  = threadIdx.x;
  const int wid  = tid >> 6;
  const int lane = tid & 63;
  const int l15  = lane & 15;
  const int l4   = lane >> 4;
  const int t0   = blockIdx.x * 64;

  // which doc does this tile live in (tiles never straddle docs)
  int off = 0, doc = 0;
  while (doc < 15) {
    const int len = 1024 + 128 * doc;
    if (t0 < off + len) break;
    off += len; ++doc;
  }
  const long tgt0 = (long)doc * MAXLEN + (t0 - off);

  const float*          aBase = A  + (size_t)(t0 + l15) * K_DIM + l4 * 8;
  const unsigned short* bBase = Wt + (size_t)(wid * 64 + l15) * K_DIM + l4 * 8;

  f32x4 acc[4][4];
#pragma unroll
  for (int m = 0; m < 4; ++m)
#pragma unroll
    for (int n = 0; n < 4; ++n) acc[m][n] = f32x4{0.f, 0.f, 0.f, 0.f};

  f32x4  apre[2][4][2];   // [buf][m-frag][half]
  bf16x8 bpre[2][4];      // [buf][n-frag]

#define LOADA(buf, kb)                                                         \
  {                                                                            \
    _Pragma("unroll") for (int m = 0; m < 4; ++m) {                            \
      apre[buf][m][0] = *(const f32x4*)(aBase + (size_t)m * 16 * K_DIM + (kb));     \
      apre[buf][m][1] = *(const f32x4*)(aBase + (size_t)m * 16 * K_DIM + (kb) + 4); \
    }                                                                          \
  }
#define LOADB(buf, kb)                                                         \
  {                                                                            \
    _Pragma("unroll") for (int n = 0; n < 4; ++n) {                            \
      bpre[buf][n] = *(const bf16x8*)(bBase + (size_t)n * 16 * K_DIM + (kb));  \
    }                                                                          \
  }

  LOADA(0, 0)
  LOADB(0, 0)
  LOADA(1, 32)
  LOADB(1, 32)

#pragma unroll
  for (int kt = 0; kt < NKT; ++kt) {
    const int cur = kt & 1;          // constant after full unroll
    const int kb2 = (kt + 2) * 32;

    // fp32 -> bf16 fragments (consumes apre[cur]; forces vmcnt wait on step kt)
    bf16x8 af[4];
#pragma unroll
    for (int m = 0; m < 4; ++m) {
      u32x4 u;
      u[0] = cvtpk(apre[cur][m][0][0], apre[cur][m][0][1]);
      u[1] = cvtpk(apre[cur][m][0][2], apre[cur][m][0][3]);
      u[2] = cvtpk(apre[cur][m][1][0], apre[cur][m][1][1]);
      u[3] = cvtpk(apre[cur][m][1][2], apre[cur][m][1][3]);
      af[m] = __builtin_bit_cast(bf16x8, u);
    }

    // refill A buffer for kt+2 (HBM stream) — in flight across next step
    if (kt < NKT - 2) LOADA(cur, kb2)

#pragma unroll
    for (int m = 0; m < 4; ++m)
#pragma unroll
      for (int n = 0; n < 4; ++n)
        acc[m][n] = __builtin_amdgcn_mfma_f32_16x16x32_bf16(af[m], bpre[cur][n], acc[m][n], 0, 0, 0);

    // refill B buffer for kt+2 (L2-resident) after its last use above
    if (kt < NKT - 2) LOADB(cur, kb2)
  }

  // epilogue: bias + scatter to padded rows
  float bc[4];
#pragma unroll
  for (int n = 0; n < 4; ++n) bc[n] = bias[wid * 64 + n * 16 + l15];

#pragma unroll
  for (int m = 0; m < 4; ++m)
#pragma unroll
    for (int n = 0; n < 4; ++n) {
      const size_t base = (size_t)(tgt0 + m * 16 + l4 * 4) * N_DIM + wid * 64 + n * 16 + l15;
#pragma unroll
      for (int j = 0; j < 4; ++j)
        out[base + (size_t)j * N_DIM] = acc[m][n][j] + bc[n];
    }
#undef LOADA
#undef LOADB
}

// ---------------------------------------------------------------------------
extern "C" void kernel_launch(void* const* d_in, const int* in_sizes, int n_in,
                              void* d_out, int out_size, void* d_ws, size_t ws_size,
                              hipStream_t stream) {
  const float* A    = (const float*)d_in[0];   // [31744, 768]
  const float* W    = (const float*)d_in[1];   // [768, 256]
  const float* bias = (const float*)d_in[2];   // [256]
  float* out = (float*)d_out;                  // [16, 2944, 256]
  unsigned short* Wt = (unsigned short*)d_ws;  // [256][768] bf16

  wt_transpose<<<48, 256, 0, stream>>>(W, Wt);
  zero_pad<<<(16 * MAXLEN * 64) / 256, 256, 0, stream>>>(out);
  gemm_scatter<<<T_TOTAL / 64, 256, 0, stream>>>(A, Wt, bias, out);
}